// Round 8
// baseline (939.384 us; speedup 1.0000x reference)
//
#include <hip/hip_runtime.h>
#include <hip/hip_bf16.h>
#include <cstdint>
#include <cstddef>

#define N_NODES 50000
#define N_EDGES 600000
#define DF 128
#define N_ETYPES 4
#define N_STEPS 5
#define SCAN_NB 196        // ceil(50000/256)
#define GRU_TILES 3125     // 50000/16 exact
#define GRU_BLOCKS 512     // 2 blocks/CU
#define LSTRIDE 130        // k_gru LDS row stride (floats): 2-way bank alias only (free)
#define FS_ROW 140         // k_fused S row stride (f16): 16 nodes*8 + pad

typedef _Float16 f16x8 __attribute__((ext_vector_type(8)));
typedef _Float16 f16x4 __attribute__((ext_vector_type(4)));
typedef _Float16 f16x2 __attribute__((ext_vector_type(2)));
typedef float f32x4 __attribute__((ext_vector_type(4)));

__device__ __forceinline__ float sigmoid_fast(float x) {
    return 1.0f / (1.0f + __expf(-x));
}
__device__ __forceinline__ float tanh_fast(float x) {
    return 1.0f - 2.0f / (__expf(2.0f * x) + 1.0f);
}

// ---------------- setup kernels (once per launch) ----------------

// Wl -> f16; build concatenated GRU B matrix Bc[g*128+c][k]: k<128 -> wih, else whh
__global__ __launch_bounds__(256) void k_cvt_w(
    const float* __restrict__ Wl, const float* __restrict__ wih,
    const float* __restrict__ whh, _Float16* __restrict__ Wl_h,
    _Float16* __restrict__ Bc) {
    int i = blockIdx.x * 256 + threadIdx.x;          // grid covers 98304
    if (i < N_ETYPES * DF * DF) Wl_h[i] = (_Float16)Wl[i];
    int row = i >> 8;                                // 0..383 = g*128 + c
    int k = i & 255;
    float v = (k < 128) ? wih[row * 128 + k] : whh[row * 128 + (k - 128)];
    Bc[i] = (_Float16)v;
}

__global__ __launch_bounds__(256) void k_cvt_h(
    const float* __restrict__ h, _Float16* __restrict__ hh, int n4) {
    int i = blockIdx.x * 256 + threadIdx.x;
    if (i < n4) {
        float4 v = ((const float4*)h)[i];
        f16x4 o;
        o.x = (_Float16)v.x; o.y = (_Float16)v.y;
        o.z = (_Float16)v.z; o.w = (_Float16)v.w;
        ((f16x4*)hh)[i] = o;
    }
}

__global__ __launch_bounds__(256) void k_hist(
    const int* __restrict__ dst, int* __restrict__ deg, int E) {
    int i = blockIdx.x * 256 + threadIdx.x;
    if (i < E) atomicAdd(&deg[dst[i]], 1);
}

// hierarchical exclusive scan over deg[0..N)
__global__ __launch_bounds__(256) void k_part(
    const int* __restrict__ deg, int* __restrict__ part, int N) {
    __shared__ int s[256];
    int t = threadIdx.x, i = blockIdx.x * 256 + t;
    s[t] = (i < N) ? deg[i] : 0;
    __syncthreads();
    for (int off = 128; off > 0; off >>= 1) {
        if (t < off) s[t] += s[t + off];
        __syncthreads();
    }
    if (t == 0) part[blockIdx.x] = s[0];
}

__global__ __launch_bounds__(256) void k_scan1(int* __restrict__ part, int nb) {
    __shared__ int s[256];
    int t = threadIdx.x;
    int v = (t < nb) ? part[t] : 0;
    s[t] = v;
    __syncthreads();
    for (int off = 1; off < 256; off <<= 1) {
        int u = (t >= off) ? s[t - off] : 0;
        __syncthreads();
        s[t] += u;
        __syncthreads();
    }
    if (t < nb) part[t] = s[t] - v;
}

__global__ __launch_bounds__(256) void k_row(
    const int* __restrict__ deg, const int* __restrict__ part,
    int* __restrict__ row_start, int* __restrict__ cursor, int N) {
    __shared__ int s[256];
    int t = threadIdx.x, i = blockIdx.x * 256 + t;
    int d = (i < N) ? deg[i] : 0;
    s[t] = d;
    __syncthreads();
    for (int off = 1; off < 256; off <<= 1) {
        int u = (t >= off) ? s[t - off] : 0;
        __syncthreads();
        s[t] += u;
        __syncthreads();
    }
    int rs = part[blockIdx.x] + s[t] - d;
    if (i < N) {
        row_start[i] = rs;
        cursor[i] = rs;
        if (i == N - 1) row_start[N] = rs + d;
    }
}

__global__ __launch_bounds__(256) void k_fill(
    const int* __restrict__ src, const int* __restrict__ dst,
    const int* __restrict__ ety, int* __restrict__ cursor,
    int* __restrict__ csr, int E) {
    int i = blockIdx.x * 256 + threadIdx.x;
    if (i < E) {
        int slot = atomicAdd(&cursor[dst[i]], 1);
        csr[slot] = src[i] | ((ety[i] - 1) << 16);   // src < 65536, et in 0..3
    }
}

// ---------------- per-step kernels ----------------

// Fused transform+aggregate via swapped algebra:
//   a[n] = sum_k W_k * (sum_{in-edges of n, type k} h[src]) + sum_k cnt_k(n)*b_k
// One block per 16-node tile.
// Phase 1: per-type gather-sums of h into LDS S (frag-major, f16) + type counts.
// Phase 2: 4x K=128 MFMA GEMM vs L2-resident weights, bias via counts.
__global__ __launch_bounds__(256, 4) void k_fused(
    const _Float16* __restrict__ hh, const _Float16* __restrict__ Wl,
    const float* __restrict__ b_lin, const int* __restrict__ row_start,
    const int* __restrict__ csr, _Float16* __restrict__ ah) {
    __shared__ _Float16 S[64 * FS_ROW];              // [(t*4+kt)*4+q][node*8+j]
    __shared__ float CNT[16][4];
    const int wave = threadIdx.x >> 6, lane = threadIdx.x & 63;
    const int g4 = lane >> 4, c8 = lane & 15;
    const int tile = blockIdx.x;

    // ---- phase 1: gather. wave w owns nodes w*4..w*4+3 of the tile.
#pragma unroll
    for (int v = 0; v < 4; v++) {
        const int node = wave * 4 + v;
        const int n = tile * 16 + node;
        const int beg = row_start[n], end = row_start[n + 1];
        float acc[4][8];
        float cnt[4] = {0.f, 0.f, 0.f, 0.f};
#pragma unroll
        for (int t = 0; t < 4; t++)
#pragma unroll
            for (int j = 0; j < 8; j++) acc[t][j] = 0.f;
        for (int e = beg; e < end; e += 8) {
            int i0 = e + g4, i1 = e + 4 + g4;
            float m0 = (i0 < end) ? 1.f : 0.f;
            float m1 = (i1 < end) ? 1.f : 0.f;
            int j0 = (i0 < end) ? i0 : beg;
            int j1 = (i1 < end) ? i1 : beg;
            int p0 = csr[j0], p1 = csr[j1];
            int et0 = p0 >> 16, et1 = p1 >> 16;
            const f16x8 x0 = *(const f16x8*)(hh + (((size_t)(p0 & 0xFFFF)) << 7) + c8 * 8);
            const f16x8 x1 = *(const f16x8*)(hh + (((size_t)(p1 & 0xFFFF)) << 7) + c8 * 8);
#pragma unroll
            for (int t = 0; t < 4; t++) {
                float f0 = (et0 == t) ? m0 : 0.f;
                float f1 = (et1 == t) ? m1 : 0.f;
                cnt[t] += f0 + f1;
#pragma unroll
                for (int j = 0; j < 8; j++)
                    acc[t][j] += f0 * (float)x0[j] + f1 * (float)x1[j];
            }
        }
        // reduce across the 4 edge-slots (lanes l, l^16, l^32, l^48)
#pragma unroll
        for (int t = 0; t < 4; t++) {
#pragma unroll
            for (int j = 0; j < 8; j++) {
                acc[t][j] += __shfl_xor(acc[t][j], 32, 64);
                acc[t][j] += __shfl_xor(acc[t][j], 16, 64);
            }
            cnt[t] += __shfl_xor(cnt[t], 32, 64);
            cnt[t] += __shfl_xor(cnt[t], 16, 64);
        }
        if (lane < 16) {
            const int kt = c8 >> 2, q = c8 & 3;
#pragma unroll
            for (int t = 0; t < 4; t++) {
                f16x8 o;
#pragma unroll
                for (int j = 0; j < 8; j++) o[j] = (_Float16)acc[t][j];
                *(f16x8*)&S[((t * 4 + kt) * 4 + q) * FS_ROW + node * 8] = o;
            }
        }
        if (lane == 0) {
            CNT[node][0] = cnt[0]; CNT[node][1] = cnt[1];
            CNT[node][2] = cnt[2]; CNT[node][3] = cnt[3];
        }
    }
    __syncthreads();

    // ---- phase 2: a_tile = sum_k S_k @ W_k^T + cnt*b. Wave w -> ft {2w, 2w+1}.
    const int m = lane & 15, q = lane >> 4;
    f16x8 A[4][4];
#pragma unroll
    for (int t = 0; t < 4; t++)
#pragma unroll
        for (int kt = 0; kt < 4; kt++)
            A[t][kt] = *(const f16x8*)&S[((t * 4 + kt) * 4 + q) * FS_ROW + m * 8];
#pragma unroll
    for (int f = 0; f < 2; f++) {
        const int ft = wave * 2 + f;
        f32x4 a = {0.f, 0.f, 0.f, 0.f};
#pragma unroll
        for (int t = 0; t < 4; t++) {
            const _Float16* wrow = Wl + (size_t)t * DF * DF + (size_t)(ft * 16 + m) * DF + q * 8;
#pragma unroll
            for (int kt = 0; kt < 4; kt++)
                a = __builtin_amdgcn_mfma_f32_16x16x32_f16(
                    A[t][kt], *(const f16x8*)(wrow + kt * 32), a, 0, 0, 0);
        }
        const int c = ft * 16 + m;
        const float bl0 = b_lin[c], bl1 = b_lin[128 + c];
        const float bl2 = b_lin[256 + c], bl3 = b_lin[384 + c];
#pragma unroll
        for (int i = 0; i < 4; i++) {
            const int row = q * 4 + i;
            float bias = CNT[row][0] * bl0 + CNT[row][1] * bl1 +
                         CNT[row][2] * bl2 + CNT[row][3] * bl3;
            ah[(((size_t)(tile * 16 + row)) << 7) + c] = (_Float16)(a[i] + bias);
        }
    }
}

// GRU, gate-parallel: one block per 16-row tile computes ALL 384 output cols.
// 12 waves = 3 gates x 4 col-slices; B-slices persistent in VGPRs. 512 blocks
// (2/CU) + double-buffered X -> one barrier per tile, cross-block latency hiding.
__global__ __launch_bounds__(768, 3) void k_gru(
    const _Float16* __restrict__ ah, const _Float16* __restrict__ hh,
    const _Float16* __restrict__ Bc, const float* __restrict__ b_ih,
    const float* __restrict__ b_hh, _Float16* __restrict__ hh_next,
    float* __restrict__ out_f32) {
    __shared__ float X[2][4 * 16 * LSTRIDE];         // double-buffered exchange
    const int wave = threadIdx.x >> 6, lane = threadIdx.x & 63;
    const int col16 = lane & 15, quad = lane >> 4;
    const int g = wave >> 2;                         // gate 0..2
    const int s = wave & 3;                          // col-slice of 32

    f16x8 b[2][8];
#pragma unroll
    for (int ct = 0; ct < 2; ct++) {
        const _Float16* bp = Bc + (((size_t)(g * 128 + s * 32 + ct * 16 + col16)) << 8) + quad * 8;
#pragma unroll
        for (int kt = 0; kt < 8; kt++) b[ct][kt] = *(const f16x8*)(bp + kt * 32);
    }

    int buf = 0;
    for (int tile = blockIdx.x; tile < GRU_TILES; tile += GRU_BLOCKS) {
        float* Xb = X[buf];
        const int r0 = tile * 16;
        const int arow = r0 + col16;
        f16x8 A[8];                                  // kt<4 = a, kt>=4 = h
        const _Float16* ap = ah + ((size_t)arow << 7) + quad * 8;
        const _Float16* hp = hh + ((size_t)arow << 7) + quad * 8;
#pragma unroll
        for (int kt = 0; kt < 4; kt++) A[kt] = *(const f16x8*)(ap + kt * 32);
#pragma unroll
        for (int kt = 0; kt < 4; kt++) A[4 + kt] = *(const f16x8*)(hp + kt * 32);

        f32x4 acc[2][2];                             // [khalf-set][ct]; g<2 uses set 0 only
#pragma unroll
        for (int u = 0; u < 2; u++)
#pragma unroll
            for (int ct = 0; ct < 2; ct++) acc[u][ct] = (f32x4){0.f, 0.f, 0.f, 0.f};
#pragma unroll
        for (int kt = 0; kt < 8; kt++) {
            const int set = (g == 2 && kt >= 4) ? 1 : 0;
#pragma unroll
            for (int ct = 0; ct < 2; ct++)
                acc[set][ct] = __builtin_amdgcn_mfma_f32_16x16x32_f16(
                    A[kt], b[ct][kt], acc[set][ct], 0, 0, 0);
        }

        // acc -> LDS exchange
#pragma unroll
        for (int ct = 0; ct < 2; ct++) {
            const int cbase = s * 32 + ct * 16 + col16;
            if (g < 2) {
#pragma unroll
                for (int i = 0; i < 4; i++)
                    Xb[g * (16 * LSTRIDE) + (quad * 4 + i) * LSTRIDE + cbase] = acc[0][ct][i];
            } else {
#pragma unroll
                for (int i = 0; i < 4; i++) {
                    Xb[2 * (16 * LSTRIDE) + (quad * 4 + i) * LSTRIDE + cbase] = acc[0][ct][i];
                    Xb[3 * (16 * LSTRIDE) + (quad * 4 + i) * LSTRIDE + cbase] = acc[1][ct][i];
                }
            }
        }
        __syncthreads();

        // epilogue: 2048 elems over 768 threads
#pragma unroll
        for (int pazz = 0; pazz < 3; pazz++) {
            int e = threadIdx.x + pazz * 768;
            if (e < 2048) {
                int row = e >> 7, col = e & 127;
                float vr = Xb[0 * (16 * LSTRIDE) + row * LSTRIDE + col];
                float vz = Xb[1 * (16 * LSTRIDE) + row * LSTRIDE + col];
                float vin = Xb[2 * (16 * LSTRIDE) + row * LSTRIDE + col];
                float vhn = Xb[3 * (16 * LSTRIDE) + row * LSTRIDE + col];
                float r = sigmoid_fast(vr + b_ih[col] + b_hh[col]);
                float z = sigmoid_fast(vz + b_ih[128 + col] + b_hh[128 + col]);
                float nn = tanh_fast(vin + b_ih[256 + col] + r * (vhn + b_hh[256 + col]));
                size_t idx = ((size_t)(r0 + row) << 7) + col;
                float hprev = (float)hh[idx];
                float hv = (1.f - z) * nn + z * hprev;
                hh_next[idx] = (_Float16)hv;
                if (out_f32) out_f32[idx] = hv;
            }
        }
        buf ^= 1;   // next tile writes the other buffer; barrier above separates reuse
    }
}

// ---------------- launch ----------------

extern "C" void kernel_launch(void* const* d_in, const int* in_sizes, int n_in,
                              void* d_out, int out_size, void* d_ws, size_t ws_size,
                              hipStream_t stream) {
    const float* h0    = (const float*)d_in[0];
    const int*   src   = (const int*)d_in[1];
    const int*   dst   = (const int*)d_in[2];
    const int*   ety   = (const int*)d_in[3];
    const float* W_lin = (const float*)d_in[4];
    const float* b_lin = (const float*)d_in[5];
    const float* w_ih  = (const float*)d_in[6];
    const float* w_hh  = (const float*)d_in[7];
    const float* b_ih  = (const float*)d_in[8];
    const float* b_hh  = (const float*)d_in[9];
    float* hout = (float*)d_out;

    char* p = (char*)d_ws;
    auto alloc = [&](size_t bytes) -> char* {
        char* r = p;
        p += (bytes + 255) & ~(size_t)255;
        return r;
    };
    _Float16* h_a    = (_Float16*)alloc((size_t)N_NODES * DF * 2);
    _Float16* h_b    = (_Float16*)alloc((size_t)N_NODES * DF * 2);
    _Float16* a_half = (_Float16*)alloc((size_t)N_NODES * DF * 2);
    _Float16* Wl_h   = (_Float16*)alloc((size_t)N_ETYPES * DF * DF * 2);
    _Float16* Bc     = (_Float16*)alloc((size_t)3 * DF * 2 * DF * 2);   // [384][256] f16
    int* deg       = (int*)alloc((size_t)N_NODES * 4);
    int* row_start = (int*)alloc((size_t)(N_NODES + 1) * 4);
    int* cursor    = (int*)alloc((size_t)N_NODES * 4);
    int* csr       = (int*)alloc((size_t)N_EDGES * 4);
    int* part      = (int*)alloc((size_t)SCAN_NB * 4);

    hipMemsetAsync(deg, 0, (size_t)N_NODES * 4, stream);
    k_cvt_w<<<384, 256, 0, stream>>>(W_lin, w_ih, w_hh, Wl_h, Bc);
    k_cvt_h<<<(N_NODES * DF / 4 + 255) / 256, 256, 0, stream>>>(h0, h_a, N_NODES * DF / 4);
    k_hist<<<(N_EDGES + 255) / 256, 256, 0, stream>>>(dst, deg, N_EDGES);
    k_part<<<SCAN_NB, 256, 0, stream>>>(deg, part, N_NODES);
    k_scan1<<<1, 256, 0, stream>>>(part, SCAN_NB);
    k_row<<<SCAN_NB, 256, 0, stream>>>(deg, part, row_start, cursor, N_NODES);
    k_fill<<<(N_EDGES + 255) / 256, 256, 0, stream>>>(src, dst, ety, cursor, csr, N_EDGES);

    _Float16* hc = h_a;
    _Float16* hn = h_b;
    for (int s = 0; s < N_STEPS; s++) {
        k_fused<<<GRU_TILES, 256, 0, stream>>>(hc, Wl_h, b_lin, row_start, csr, a_half);
        float* of = (s == N_STEPS - 1) ? hout : nullptr;
        k_gru<<<GRU_BLOCKS, 768, 0, stream>>>(a_half, hc, Bc, b_ih, b_hh, hn, of);
        _Float16* tmp = hc; hc = hn; hn = tmp;
    }
}

// Round 9
// 868.790 us; speedup vs baseline: 1.0813x; 1.0813x over previous
//
#include <hip/hip_runtime.h>
#include <hip/hip_bf16.h>
#include <cstdint>
#include <cstddef>

#define N_NODES 50000
#define N_EDGES 600000
#define DF 128
#define N_ETYPES 4
#define N_STEPS 5
#define SCAN_NB 196        // ceil(50000/256)
#define GRU_TILES 3125     // 50000/16 exact
#define GRU_BLOCKS 256     // 1 block/CU
#define LSTRIDE 130        // k_gru X row stride (floats): 2-way bank alias only (free)
#define HSTRIDE 136        // k_gru H tile row stride (f16)
#define TSTRIDE 136        // k_lin LDS tile row stride (f16)

typedef _Float16 f16x8 __attribute__((ext_vector_type(8)));
typedef _Float16 f16x4 __attribute__((ext_vector_type(4)));
typedef _Float16 f16x2 __attribute__((ext_vector_type(2)));
typedef float f32x4 __attribute__((ext_vector_type(4)));

__device__ __forceinline__ float sigmoid_fast(float x) {
    return 1.0f / (1.0f + __expf(-x));
}
__device__ __forceinline__ float tanh_fast(float x) {
    return 1.0f - 2.0f / (__expf(2.0f * x) + 1.0f);
}

// ---------------- setup kernels (once per launch) ----------------

// Wl -> f16; build concatenated GRU B matrix Bc[g*128+c][k]: k<128 -> wih, else whh
__global__ __launch_bounds__(256) void k_cvt_w(
    const float* __restrict__ Wl, const float* __restrict__ wih,
    const float* __restrict__ whh, _Float16* __restrict__ Wl_h,
    _Float16* __restrict__ Bc) {
    int i = blockIdx.x * 256 + threadIdx.x;          // grid covers 98304
    if (i < N_ETYPES * DF * DF) Wl_h[i] = (_Float16)Wl[i];
    int row = i >> 8;                                // 0..383 = g*128 + c
    int k = i & 255;
    float v = (k < 128) ? wih[row * 128 + k] : whh[row * 128 + (k - 128)];
    Bc[i] = (_Float16)v;
}

__global__ __launch_bounds__(256) void k_cvt_h(
    const float* __restrict__ h, _Float16* __restrict__ hh, int n4) {
    int i = blockIdx.x * 256 + threadIdx.x;
    if (i < n4) {
        float4 v = ((const float4*)h)[i];
        f16x4 o;
        o.x = (_Float16)v.x; o.y = (_Float16)v.y;
        o.z = (_Float16)v.z; o.w = (_Float16)v.w;
        ((f16x4*)hh)[i] = o;
    }
}

__global__ __launch_bounds__(256) void k_hist(
    const int* __restrict__ dst, int* __restrict__ deg, int E) {
    int i = blockIdx.x * 256 + threadIdx.x;
    if (i < E) atomicAdd(&deg[dst[i]], 1);
}

// hierarchical exclusive scan over deg[0..N)
__global__ __launch_bounds__(256) void k_part(
    const int* __restrict__ deg, int* __restrict__ part, int N) {
    __shared__ int s[256];
    int t = threadIdx.x, i = blockIdx.x * 256 + t;
    s[t] = (i < N) ? deg[i] : 0;
    __syncthreads();
    for (int off = 128; off > 0; off >>= 1) {
        if (t < off) s[t] += s[t + off];
        __syncthreads();
    }
    if (t == 0) part[blockIdx.x] = s[0];
}

__global__ __launch_bounds__(256) void k_scan1(int* __restrict__ part, int nb) {
    __shared__ int s[256];
    int t = threadIdx.x;
    int v = (t < nb) ? part[t] : 0;
    s[t] = v;
    __syncthreads();
    for (int off = 1; off < 256; off <<= 1) {
        int u = (t >= off) ? s[t - off] : 0;
        __syncthreads();
        s[t] += u;
        __syncthreads();
    }
    if (t < nb) part[t] = s[t] - v;
}

__global__ __launch_bounds__(256) void k_row(
    const int* __restrict__ deg, const int* __restrict__ part,
    int* __restrict__ row_start, int* __restrict__ cursor, int N) {
    __shared__ int s[256];
    int t = threadIdx.x, i = blockIdx.x * 256 + t;
    int d = (i < N) ? deg[i] : 0;
    s[t] = d;
    __syncthreads();
    for (int off = 1; off < 256; off <<= 1) {
        int u = (t >= off) ? s[t - off] : 0;
        __syncthreads();
        s[t] += u;
        __syncthreads();
    }
    int rs = part[blockIdx.x] + s[t] - d;
    if (i < N) {
        row_start[i] = rs;
        cursor[i] = rs;
        if (i == N - 1) row_start[N] = rs + d;
    }
}

__global__ __launch_bounds__(256) void k_fill(
    const int* __restrict__ src, const int* __restrict__ dst,
    const int* __restrict__ ety, int* __restrict__ cursor,
    int* __restrict__ csr, int E) {
    int i = blockIdx.x * 256 + threadIdx.x;
    if (i < E) {
        int slot = atomicAdd(&cursor[dst[i]], 1);
        csr[slot] = src[i] | ((ety[i] - 1) << 16);   // src < 65536, et in 0..3
    }
}

// ---------------- per-step kernels ----------------

// t[k][n][f] = sum_d h[n,d] * W[k][f,d] + b_lin[k][f]   (f16 h in, f16 out)
// One etype per block (grid.y): TLP for latency hiding; weights L1-resident.
__global__ __launch_bounds__(256) void k_lin(
    const _Float16* __restrict__ hh, const _Float16* __restrict__ Wl,
    const float* __restrict__ b_lin, _Float16* __restrict__ t_out, int N) {
    __shared__ _Float16 T[4 * 16 * TSTRIDE];
    const int wave = threadIdx.x >> 6, lane = threadIdx.x & 63;
    const int col = lane & 15, quad = lane >> 4;
    const int r0 = blockIdx.x * 64 + wave * 16;
    const int ktype = blockIdx.y;
    _Float16* Tw = &T[wave * 16 * TSTRIDE];
    int arow = r0 + col; if (arow >= N) arow = N - 1;
    f16x8 a[4];
    const _Float16* hp = hh + (size_t)arow * DF + quad * 8;
#pragma unroll
    for (int kt = 0; kt < 4; kt++) a[kt] = *(const f16x8*)(hp + kt * 32);
    const _Float16* W = Wl + (size_t)ktype * DF * DF;
    _Float16* tk = t_out + (size_t)ktype * N * DF;
    f32x4 accs[8];
#pragma unroll
    for (int ft = 0; ft < 8; ft++) {
        f32x4 acc = {0.f, 0.f, 0.f, 0.f};
        const _Float16* wrow = W + (size_t)(ft * 16 + col) * DF + quad * 8;
#pragma unroll
        for (int kt = 0; kt < 4; kt++)
            acc = __builtin_amdgcn_mfma_f32_16x16x32_f16(
                a[kt], *(const f16x8*)(wrow + kt * 32), acc, 0, 0, 0);
        accs[ft] = acc;
    }
#pragma unroll
    for (int ft = 0; ft < 8; ft++) {
        float bias = b_lin[ktype * DF + ft * 16 + col];
#pragma unroll
        for (int i = 0; i < 4; i++)
            Tw[(quad * 4 + i) * TSTRIDE + ft * 16 + col] = (_Float16)(accs[ft][i] + bias);
    }
    if (r0 < N) {
#pragma unroll
        for (int j = 0; j < 4; j++) {
            int chunk = lane + 64 * j;               // 0..255
            int row = chunk >> 4, c8 = chunk & 15;
            f16x8 v = *(const f16x8*)&Tw[row * TSTRIDE + c8 * 8];
            *(f16x8*)(tk + (size_t)(r0 + row) * DF + c8 * 8) = v;
        }
    }
}

// a[n][:] = sum over incoming edges of t[et][src][:]  -> f16
// wave = 4 edge-slots x 16 lanes; 16 edges (4 gather instrs) in flight per iter.
__global__ __launch_bounds__(256) void k_agg(
    const _Float16* __restrict__ t, const int* __restrict__ row_start,
    const int* __restrict__ csr, _Float16* __restrict__ ah, int N) {
    const int wave = threadIdx.x >> 6, lane = threadIdx.x & 63;
    const int g4 = lane >> 4;                        // edge slot 0..3
    const int c8 = lane & 15;                        // col chunk: cols c8*8..+7
    const int n = blockIdx.x * 4 + wave;             // grid = N/4 exactly
    const int beg = row_start[n], end = row_start[n + 1];
    float acc[8] = {0.f, 0.f, 0.f, 0.f, 0.f, 0.f, 0.f, 0.f};
    for (int e = beg; e < end; e += 16) {
        int i0 = e + g4, i1 = e + 4 + g4, i2 = e + 8 + g4, i3 = e + 12 + g4;
        float m0 = (i0 < end) ? 1.0f : 0.0f;
        float m1 = (i1 < end) ? 1.0f : 0.0f;
        float m2 = (i2 < end) ? 1.0f : 0.0f;
        float m3 = (i3 < end) ? 1.0f : 0.0f;
        int j0 = (i0 < end) ? i0 : end - 1;
        int j1 = (i1 < end) ? i1 : end - 1;
        int j2 = (i2 < end) ? i2 : end - 1;
        int j3 = (i3 < end) ? i3 : end - 1;
        int p0 = csr[j0], p1 = csr[j1], p2 = csr[j2], p3 = csr[j3];
        f16x8 x0 = *(const f16x8*)(t + ((((size_t)(p0 >> 16)) * N + (p0 & 0xFFFF)) << 7) + c8 * 8);
        f16x8 x1 = *(const f16x8*)(t + ((((size_t)(p1 >> 16)) * N + (p1 & 0xFFFF)) << 7) + c8 * 8);
        f16x8 x2 = *(const f16x8*)(t + ((((size_t)(p2 >> 16)) * N + (p2 & 0xFFFF)) << 7) + c8 * 8);
        f16x8 x3 = *(const f16x8*)(t + ((((size_t)(p3 >> 16)) * N + (p3 & 0xFFFF)) << 7) + c8 * 8);
#pragma unroll
        for (int j = 0; j < 8; j++) acc[j] += m0 * (float)x0[j];
#pragma unroll
        for (int j = 0; j < 8; j++) acc[j] += m1 * (float)x1[j];
#pragma unroll
        for (int j = 0; j < 8; j++) acc[j] += m2 * (float)x2[j];
#pragma unroll
        for (int j = 0; j < 8; j++) acc[j] += m3 * (float)x3[j];
    }
#pragma unroll
    for (int j = 0; j < 8; j++) {
        acc[j] += __shfl_xor(acc[j], 32, 64);
        acc[j] += __shfl_xor(acc[j], 16, 64);
    }
    if (lane < 16) {
        f16x8 o;
#pragma unroll
        for (int j = 0; j < 8; j++) o[j] = (_Float16)acc[j];
        *(f16x8*)(ah + ((size_t)n << 7) + c8 * 8) = o;
    }
}

// GRU, gate-parallel, latency-engineered:
//  - B frags PINNED in VGPRs via empty asm (defeats compiler rematerialization
//    -- R7 showed VGPR_Count=60 => b[2][8] was being reloaded from L2 per tile)
//  - next tile's A prefetched before the barrier; raw s_barrier with
//    lgkmcnt(0)-only waitcnt keeps the prefetch in flight across it
//  - epilogue has ZERO global loads (hprev comes from an LDS tile written by
//    wave 0 from its A registers), so no newer vmem op forces the prefetch drain
__global__ __launch_bounds__(768, 3) void k_gru(
    const _Float16* __restrict__ ah, const _Float16* __restrict__ hh,
    const _Float16* __restrict__ Bc, const float* __restrict__ b_ih,
    const float* __restrict__ b_hh, _Float16* __restrict__ hh_next,
    float* __restrict__ out_f32) {
    __shared__ float X[4 * 16 * LSTRIDE];            // gate exchange, 33 KB
    __shared__ _Float16 H[16 * HSTRIDE];             // hprev tile, 4.25 KB
    const int wave = threadIdx.x >> 6, lane = threadIdx.x & 63;
    const int col16 = lane & 15, quad = lane >> 4;
    const int g = wave >> 2;                         // gate 0..2
    const int s = wave & 3;                          // col-slice of 32

    f16x8 b[2][8];
#pragma unroll
    for (int ct = 0; ct < 2; ct++) {
        const _Float16* bp = Bc + (((size_t)(g * 128 + s * 32 + ct * 16 + col16)) << 8) + quad * 8;
#pragma unroll
        for (int kt = 0; kt < 8; kt++) b[ct][kt] = *(const f16x8*)(bp + kt * 32);
    }
    // pin: compiler must keep these 64 VGPRs live (no remat-from-global per tile)
#pragma unroll
    for (int ct = 0; ct < 2; ct++)
#pragma unroll
        for (int kt = 0; kt < 8; kt++)
            asm volatile("" : "+v"(b[ct][kt]));

    int tile = blockIdx.x;
    f16x8 A[8];                                      // kt<4 = a, kt>=4 = h
    {
        const int arow = tile * 16 + col16;
        const _Float16* ap = ah + ((size_t)arow << 7) + quad * 8;
        const _Float16* hp = hh + ((size_t)arow << 7) + quad * 8;
#pragma unroll
        for (int kt = 0; kt < 4; kt++) A[kt] = *(const f16x8*)(ap + kt * 32);
#pragma unroll
        for (int kt = 0; kt < 4; kt++) A[4 + kt] = *(const f16x8*)(hp + kt * 32);
    }

    for (; tile < GRU_TILES; tile += GRU_BLOCKS) {
        const int r0 = tile * 16;

        f32x4 acc[2][2];                             // [khalf-set][ct]; g<2 uses set 0
#pragma unroll
        for (int u = 0; u < 2; u++)
#pragma unroll
            for (int ct = 0; ct < 2; ct++) acc[u][ct] = (f32x4){0.f, 0.f, 0.f, 0.f};
#pragma unroll
        for (int kt = 0; kt < 8; kt++) {
            const int set = (g == 2 && kt >= 4) ? 1 : 0;
#pragma unroll
            for (int ct = 0; ct < 2; ct++)
                acc[set][ct] = __builtin_amdgcn_mfma_f32_16x16x32_f16(
                    A[kt], b[ct][kt], acc[set][ct], 0, 0, 0);
        }

        // wave 0 exports its h-half A frags -> H (epilogue's hprev source)
        if (wave == 0) {
#pragma unroll
            for (int kt = 0; kt < 4; kt++)
                *(f16x8*)&H[col16 * HSTRIDE + kt * 32 + quad * 8] = A[4 + kt];
        }

        // prefetch next tile's A (stays in flight across the raw barrier)
        const int ntile = tile + GRU_BLOCKS;
        f16x8 An[8];
        if (ntile < GRU_TILES) {
            const int nrow = ntile * 16 + col16;
            const _Float16* ap = ah + ((size_t)nrow << 7) + quad * 8;
            const _Float16* hp = hh + ((size_t)nrow << 7) + quad * 8;
#pragma unroll
            for (int kt = 0; kt < 4; kt++) An[kt] = *(const f16x8*)(ap + kt * 32);
#pragma unroll
            for (int kt = 0; kt < 4; kt++) An[4 + kt] = *(const f16x8*)(hp + kt * 32);
        } else {
#pragma unroll
            for (int kt = 0; kt < 8; kt++) An[kt] = A[kt];
        }

        // acc -> X exchange
#pragma unroll
        for (int ct = 0; ct < 2; ct++) {
            const int cbase = s * 32 + ct * 16 + col16;
            if (g < 2) {
#pragma unroll
                for (int i = 0; i < 4; i++)
                    X[g * (16 * LSTRIDE) + (quad * 4 + i) * LSTRIDE + cbase] = acc[0][ct][i];
            } else {
#pragma unroll
                for (int i = 0; i < 4; i++) {
                    X[2 * (16 * LSTRIDE) + (quad * 4 + i) * LSTRIDE + cbase] = acc[0][ct][i];
                    X[3 * (16 * LSTRIDE) + (quad * 4 + i) * LSTRIDE + cbase] = acc[1][ct][i];
                }
            }
        }
        // barrier 1: drain LDS writes only; global prefetch stays outstanding
        asm volatile("s_waitcnt lgkmcnt(0)\n\ts_barrier" ::: "memory");

        // epilogue: 2048 elems over 768 threads; no global loads
#pragma unroll
        for (int pazz = 0; pazz < 3; pazz++) {
            int e = threadIdx.x + pazz * 768;
            if (e < 2048) {
                int row = e >> 7, col = e & 127;
                float vr = X[0 * (16 * LSTRIDE) + row * LSTRIDE + col];
                float vz = X[1 * (16 * LSTRIDE) + row * LSTRIDE + col];
                float vin = X[2 * (16 * LSTRIDE) + row * LSTRIDE + col];
                float vhn = X[3 * (16 * LSTRIDE) + row * LSTRIDE + col];
                float r = sigmoid_fast(vr + b_ih[col] + b_hh[col]);
                float z = sigmoid_fast(vz + b_ih[128 + col] + b_hh[128 + col]);
                float nn = tanh_fast(vin + b_ih[256 + col] + r * (vhn + b_hh[256 + col]));
                float hprev = (float)H[row * HSTRIDE + col];
                size_t idx = ((size_t)(r0 + row) << 7) + col;
                float hv = (1.f - z) * nn + z * hprev;
                hh_next[idx] = (_Float16)hv;
                if (out_f32) out_f32[idx] = hv;
            }
        }
        // barrier 2: epilogue LDS reads already consumed -> plain barrier
        asm volatile("s_barrier" ::: "memory");

#pragma unroll
        for (int kt = 0; kt < 8; kt++) A[kt] = An[kt];
    }
}

// ---------------- launch ----------------

extern "C" void kernel_launch(void* const* d_in, const int* in_sizes, int n_in,
                              void* d_out, int out_size, void* d_ws, size_t ws_size,
                              hipStream_t stream) {
    const float* h0    = (const float*)d_in[0];
    const int*   src   = (const int*)d_in[1];
    const int*   dst   = (const int*)d_in[2];
    const int*   ety   = (const int*)d_in[3];
    const float* W_lin = (const float*)d_in[4];
    const float* b_lin = (const float*)d_in[5];
    const float* w_ih  = (const float*)d_in[6];
    const float* w_hh  = (const float*)d_in[7];
    const float* b_ih  = (const float*)d_in[8];
    const float* b_hh  = (const float*)d_in[9];
    float* hout = (float*)d_out;

    char* p = (char*)d_ws;
    auto alloc = [&](size_t bytes) -> char* {
        char* r = p;
        p += (bytes + 255) & ~(size_t)255;
        return r;
    };
    _Float16* h_a    = (_Float16*)alloc((size_t)N_NODES * DF * 2);
    _Float16* h_b    = (_Float16*)alloc((size_t)N_NODES * DF * 2);
    _Float16* a_half = (_Float16*)alloc((size_t)N_NODES * DF * 2);
    _Float16* t_half = (_Float16*)alloc((size_t)N_ETYPES * N_NODES * DF * 2);
    _Float16* Wl_h   = (_Float16*)alloc((size_t)N_ETYPES * DF * DF * 2);
    _Float16* Bc     = (_Float16*)alloc((size_t)3 * DF * 2 * DF * 2);   // [384][256] f16
    int* deg       = (int*)alloc((size_t)N_NODES * 4);
    int* row_start = (int*)alloc((size_t)(N_NODES + 1) * 4);
    int* cursor    = (int*)alloc((size_t)N_NODES * 4);
    int* csr       = (int*)alloc((size_t)N_EDGES * 4);
    int* part      = (int*)alloc((size_t)SCAN_NB * 4);

    hipMemsetAsync(deg, 0, (size_t)N_NODES * 4, stream);
    k_cvt_w<<<384, 256, 0, stream>>>(W_lin, w_ih, w_hh, Wl_h, Bc);
    k_cvt_h<<<(N_NODES * DF / 4 + 255) / 256, 256, 0, stream>>>(h0, h_a, N_NODES * DF / 4);
    k_hist<<<(N_EDGES + 255) / 256, 256, 0, stream>>>(dst, deg, N_EDGES);
    k_part<<<SCAN_NB, 256, 0, stream>>>(deg, part, N_NODES);
    k_scan1<<<1, 256, 0, stream>>>(part, SCAN_NB);
    k_row<<<SCAN_NB, 256, 0, stream>>>(deg, part, row_start, cursor, N_NODES);
    k_fill<<<(N_EDGES + 255) / 256, 256, 0, stream>>>(src, dst, ety, cursor, csr, N_EDGES);

    _Float16* hc = h_a;
    _Float16* hn = h_b;
    const int nb = (N_NODES + 63) / 64;              // 782
    for (int s = 0; s < N_STEPS; s++) {
        k_lin<<<dim3(nb, N_ETYPES), 256, 0, stream>>>(hc, Wl_h, b_lin, t_half, N_NODES);
        k_agg<<<N_NODES / 4, 256, 0, stream>>>(t_half, row_start, csr, a_half, N_NODES);
        float* of = (s == N_STEPS - 1) ? hout : nullptr;
        k_gru<<<GRU_BLOCKS, 768, 0, stream>>>(a_half, hc, Bc, b_ih, b_hh, hn, of);
        _Float16* tmp = hc; hc = hn; hn = tmp;
    }
}